// Round 3
// baseline (177.211 us; speedup 1.0000x reference)
//
#include <hip/hip_runtime.h>
#include <cstdint>
#include <cstddef>

typedef unsigned short u16;
typedef u16   u16x8  __attribute__((ext_vector_type(8)));
typedef u16   u16x4  __attribute__((ext_vector_type(4)));
typedef __bf16 bf16x8 __attribute__((ext_vector_type(8)));
typedef float f32x4  __attribute__((ext_vector_type(4)));
typedef float f32x2  __attribute__((ext_vector_type(2)));

__device__ __forceinline__ float bf2f(u16 v) {
  unsigned int u = ((unsigned int)v) << 16;
  return __builtin_bit_cast(float, u);
}
__device__ __forceinline__ u16 f2bf(float f) {
  unsigned int x = __builtin_bit_cast(unsigned int, f);
  x += 0x7fffu + ((x >> 16) & 1u);   // RNE
  return (u16)(x >> 16);
}

// async global->LDS, 16B per lane. LDS dest must be wave-uniform base + lane*16.
__device__ __forceinline__ void gld_lds16(const u16* g, u16* l) {
  __builtin_amdgcn_global_load_lds(
      (const __attribute__((address_space(1))) unsigned int*)g,
      (__attribute__((address_space(3))) unsigned int*)l, 16, 0, 0);
}

// ---------------------------------------------------------------------------
// Kernel 1 (fat): blocks 0..255  -> transpose W21/W22 f32 -> bf16 Wt [n][k]
//                 blocks 256..767-> h1 = relu(x @ W1 + b1), 16 rows per block
//                                   (halves W1 L2 traffic vs 8 rows/block);
//                                   zero head rows (ws poisoned).
// 16-row h1 body is the R1-verified phase-1 code (bit-identical numerics).
// ---------------------------------------------------------------------------
__global__ __launch_bounds__(256) void k_prep(const float* __restrict__ W21,
                                              const float* __restrict__ W22,
                                              u16* __restrict__ Wt,
                                              const float* __restrict__ x,
                                              const float* __restrict__ W1,
                                              const float* __restrict__ b1,
                                              u16* __restrict__ h1,
                                              float* __restrict__ head) {
  __shared__ u16 s[64][65];
  const int b = blockIdx.x;
  if (b < 256) {
    const int mat = b >> 7;
    const int tt  = b & 127;
    const int k0  = (tt >> 3) * 64;
    const int n0  = (tt & 7) * 64;
    const float* W = mat ? W22 : W21;
    const int tx = threadIdx.x & 63;
    const int ty = threadIdx.x >> 6;
#pragma unroll
    for (int i = 0; i < 16; ++i) {
      int r = i * 4 + ty;
      s[r][tx] = f2bf(W[(size_t)(k0 + r) * 512 + n0 + tx]);
    }
    __syncthreads();
    const int nbase = mat * 512 + n0;
#pragma unroll
    for (int i = 0; i < 16; ++i) {
      int r = i * 4 + ty;
      Wt[(size_t)(nbase + r) * 1024 + k0 + tx] = s[tx][r];
    }
  } else {
    const int row0t = (b - 256) * 16;
    if (threadIdx.x < 16)
      *(f32x4*)(head + 4 * (size_t)(row0t + threadIdx.x)) = f32x4{0.f, 0.f, 0.f, 0.f};
    const int c4 = threadIdx.x * 4;
    f32x4 bv = *(const f32x4*)(b1 + c4);
    for (int g = 0; g < 2; ++g) {
      const int row0 = row0t + g * 8;
      f32x4 acc[8];
#pragma unroll
      for (int r = 0; r < 8; ++r) acc[r] = bv;
#pragma unroll
      for (int f = 0; f < 8; ++f) {
        f32x4 wv = *(const f32x4*)(W1 + f * 1024 + c4);
#pragma unroll
        for (int r = 0; r < 8; ++r) {
          float xv = x[(size_t)(row0 + r) * 8 + f];   // block-uniform -> s_load
#pragma unroll
          for (int e = 0; e < 4; ++e) acc[r][e] = fmaf(xv, wv[e], acc[r][e]);
        }
      }
#pragma unroll
      for (int r = 0; r < 8; ++r) {
        u16x4 o;
#pragma unroll
        for (int e = 0; e < 4; ++e) o[e] = f2bf(fmaxf(acc[r][e], 0.f));
        *(u16x4*)(h1 + (size_t)(row0 + r) * 1024 + c4) = o;
      }
    }
  }
}

// ---------------------------------------------------------------------------
// Kernel 2: X2-GEMM, 256x128 tile (was 128x128), 512 threads, BK=64.
// Rationale: staging is L2-BW-bound (not MFMA). Staged bytes =
// 16MB*(1024/Tn) + 2MB*(8192/Tm); 256x128 -> 192MB (vs 256MB) at full
// occupancy: 256 blocks = 1/CU, LDS 96KB (2x32K A + 2x16K B dbuf).
// 8 waves in 4x2 grid; per-wave 64x64 inner loop, XOR chunk swizzle,
// epilogue identical -> per-output accumulation order unchanged (bit-exact).
// XCD locality: id%8 = bx%8 -> per-XCD A set 4x512KB + B 2MB = 4MB L2.
// ---------------------------------------------------------------------------
__global__ __launch_bounds__(512) void k_gemm(const u16* __restrict__ A,
                                              const u16* __restrict__ Bt,
                                              const float* __restrict__ b21,
                                              const float* __restrict__ b22,
                                              const float* __restrict__ W31,
                                              const float* __restrict__ W32,
                                              float* __restrict__ head) {
  constexpr int K  = 1024;
  constexpr int BK = 64;
  constexpr int NT = K / BK;           // 16 K-tiles
  __shared__ u16 As[2][256 * 64];      // 32 KB each
  __shared__ u16 Bs[2][128 * 64];      // 16 KB each; total 96 KB -> 1 blk/CU

  const int t    = threadIdx.x;
  const int row0 = blockIdx.x * 256;   // 32 M-tiles
  const int col0 = blockIdx.y * 128;   // 8 N-tiles
  const int w    = t >> 6;
  const int lane = t & 63;
  const int wr   = w >> 1, wc = w & 1; // 4x2 wave grid, 64x64 per wave
  const int lrow = lane & 15;
  const int kq   = lane >> 4;          // frag k-chunk within a k32 step

  // A staging slots m=0..3: s = t + 512m (2048 chunks = 256 rows x 8);
  // B slots m=0..1: s = t + 512m (1024 chunks = 128 rows x 8).
  // stored chunk = s&7 holds global kchunk (s&7)^((s>>3)&7).
  const u16* gA[4];
  int loA[4];
#pragma unroll
  for (int m = 0; m < 4; ++m) {
    const int s  = t + 512 * m;
    const int gc = (s & 7) ^ ((s >> 3) & 7);
    gA[m]  = A + (size_t)(row0 + (s >> 3)) * K + gc * 8;
    loA[m] = s * 8;
  }
  const u16* gB[2];
  int loB[2];
#pragma unroll
  for (int m = 0; m < 2; ++m) {
    const int s  = t + 512 * m;
    const int gc = (s & 7) ^ ((s >> 3) & 7);
    gB[m]  = Bt + (size_t)(col0 + (s >> 3)) * K + gc * 8;
    loB[m] = s * 8;
  }
  // read-side physical chunk offsets for k32-steps 0/1 (logical chunk
  // s32*4+kq at row r -> stored chunk (s32*4+kq)^(r&7); r&7 == lrow&7)
  const int po0 = (((0 * 4) + kq) ^ (lrow & 7)) * 8;
  const int po1 = (((1 * 4) + kq) ^ (lrow & 7)) * 8;

  f32x4 acc[4][4];
#pragma unroll
  for (int i = 0; i < 4; ++i)
#pragma unroll
    for (int j = 0; j < 4; ++j) acc[i][j] = f32x4{0.f, 0.f, 0.f, 0.f};

  // prologue: DMA tile 0 into buffer 0
#pragma unroll
  for (int m = 0; m < 4; ++m) gld_lds16(gA[m], As[0] + loA[m]);
#pragma unroll
  for (int m = 0; m < 2; ++m) gld_lds16(gB[m], Bs[0] + loB[m]);

  for (int kt = 0; kt < NT; ++kt) {
    const int cur = kt & 1, nxt = cur ^ 1;
    __syncthreads();                   // drains DMA into buf[cur]; orders WAR

    if (kt + 1 < NT) {                 // DMA next tile into buf[nxt]
      const int ko = (kt + 1) * BK;
#pragma unroll
      for (int m = 0; m < 4; ++m) gld_lds16(gA[m] + ko, As[nxt] + loA[m]);
#pragma unroll
      for (int m = 0; m < 2; ++m) gld_lds16(gB[m] + ko, Bs[nxt] + loB[m]);
    }

#pragma unroll
    for (int s32 = 0; s32 < 2; ++s32) {
      const int po = s32 ? po1 : po0;
      bf16x8 af[4], bfr[4];
#pragma unroll
      for (int i = 0; i < 4; ++i)
        af[i] = __builtin_bit_cast(bf16x8,
            *(const u16x8*)(As[cur] + (wr * 64 + i * 16 + lrow) * 64 + po));
#pragma unroll
      for (int j = 0; j < 4; ++j)
        bfr[j] = __builtin_bit_cast(bf16x8,
            *(const u16x8*)(Bs[cur] + (wc * 64 + j * 16 + lrow) * 64 + po));
#pragma unroll
      for (int i = 0; i < 4; ++i)
#pragma unroll
        for (int j = 0; j < 4; ++j)
          acc[i][j] = __builtin_amdgcn_mfma_f32_16x16x32_bf16(af[i], bfr[j], acc[i][j], 0, 0, 0);
    }
  }

  // ---- fused head epilogue ----
  // acc[i][j][rr]: row = row0+wr*64+i*16+kq*4+rr, col = col0+wc*64+j*16+lrow
  const bool isX21 = (col0 < 512);
  const float* Wh  = isX21 ? W31 : W32;      // [512][2] row-major
  const int   hoff = isX21 ? 0 : 2;

  float hx[16], hy[16];
#pragma unroll
  for (int n = 0; n < 16; ++n) { hx[n] = 0.f; hy[n] = 0.f; }
#pragma unroll
  for (int j = 0; j < 4; ++j) {
    int col  = col0 + wc * 64 + j * 16 + lrow;
    int wcol = col & 511;
    f32x2 wv = *(const f32x2*)(Wh + 2 * wcol);
    float bias = isX21 ? b21[col] : b22[wcol];
#pragma unroll
    for (int i = 0; i < 4; ++i)
#pragma unroll
      for (int rr = 0; rr < 4; ++rr) {
        float v = fmaxf(acc[i][j][rr] + bias, 0.f);
        hx[i * 4 + rr] = fmaf(v, wv[0], hx[i * 4 + rr]);
        hy[i * 4 + rr] = fmaf(v, wv[1], hy[i * 4 + rr]);
      }
  }
  // reduce across the 16 col-lanes (masks 1,2,4,8 stay inside the group)
#pragma unroll
  for (int m = 1; m <= 8; m <<= 1) {
#pragma unroll
    for (int n = 0; n < 16; ++n) {
      hx[n] += __shfl_xor(hx[n], m, 64);
      hy[n] += __shfl_xor(hy[n], m, 64);
    }
  }
  if (lrow == 0) {
#pragma unroll
    for (int i = 0; i < 4; ++i)
#pragma unroll
      for (int rr = 0; rr < 4; ++rr) {
        int row = row0 + wr * 64 + i * 16 + kq * 4 + rr;
        atomicAdd(head + 4 * (size_t)row + hoff,     hx[i * 4 + rr]);
        atomicAdd(head + 4 * (size_t)row + hoff + 1, hy[i * 4 + rr]);
      }
  }
}

// ---------------------------------------------------------------------------
// Kernel 3: rank-2 dual PGD QP. One thread per row; heads precomputed.
// Inner loop packed as f32x2 pairs (m, m+4) -> v_pk_{mul,add,fma,max}_f32.
// Sum trees and op order bit-identical to the scalar version (verified R1/R2:
// absmax unchanged at 0.015625).
// ---------------------------------------------------------------------------
__global__ __launch_bounds__(256) void k_qp(const float* __restrict__ x,
                                            const float* __restrict__ mean_,
                                            const float* __restrict__ std_,
                                            const float* __restrict__ head,
                                            const float* __restrict__ b31,
                                            const float* __restrict__ b32,
                                            const float* __restrict__ obstacles,
                                            float* __restrict__ out) {
  const int r = blockIdx.x * 256 + threadIdx.x;
  f32x4 hd = *(const f32x4*)(head + 4 * (size_t)r);
  float p0  = hd[0] + b31[0];
  float p1v = hd[1] + b31[1];
  float pp1 = 4.f / (1.f + expf(-(hd[2] + b32[0])));
  float pp2 = 4.f / (1.f + expf(-(hd[3] + b32[1])));

  const f32x4* xp = (const f32x4*)(x + (size_t)r * 8);
  f32x4 xa = xp[0], xb = xp[1];
  float px = xa[0] * std_[0] + mean_[0];
  float py = xa[1] * std_[1] + mean_[1];
  float th = xa[2] * std_[2] + mean_[2];
  float v  = xa[3] * std_[3] + mean_[3];
  float ax = xb[0] * std_[4] + mean_[4];
  float ay = xb[1] * std_[5] + mean_[5];
  float st = sinf(th), ct = cosf(th);
  float Lf2b = 2.f * v * v;

  float G0[9], G1[9], q[9];
  float s00 = 0.f, s01 = 0.f, s11 = 0.f;
#pragma unroll
  for (int m = 0; m < 9; ++m) {
    float ox, oy, orad;
    if (m < 8) {
      ox = obstacles[m * 3]; oy = obstacles[m * 3 + 1]; orad = obstacles[m * 3 + 2];
    } else { ox = ax; oy = ay; orad = 0.5f; }
    float R  = 0.6f + orad;                  // AGENT_RADIUS + orad + SAFETY
    float dx = px - ox, dy = py - oy;
    float bar  = dx * dx + dy * dy - R * R;
    float dct  = dx * ct + dy * st;
    float bdot = 2.f * v * dct;
    float g0 = 2.f * v * (dx * st - dy * ct);   // -LgLfbu1
    float g1 = -2.f * dct;                      // -LgLfbu2
    float h  = Lf2b + (pp1 + pp2) * bdot + pp1 * pp2 * bar;
    G0[m] = g0; G1[m] = g1;
    q[m] = g0 * p0 + g1 * p1v + h;
    s00 += g0 * g0; s01 += g0 * g1; s11 += g1 * g1;
  }
  float L = sqrtf(s00 * s00 + 2.f * s01 * s01 + s11 * s11) + 1e-6f;
  float alpha = 1.f / L;

  // pack pairs (m, m+4); m=8 stays scalar
  f32x2 G0p[4], G1p[4], qp2[4], lamp[4];
#pragma unroll
  for (int j = 0; j < 4; ++j) {
    G0p[j] = f32x2{G0[j], G0[j + 4]};
    G1p[j] = f32x2{G1[j], G1[j + 4]};
    qp2[j] = f32x2{q[j],  q[j + 4]};
    lamp[j] = f32x2{0.f, 0.f};
  }
  float G08 = G0[8], G18 = G1[8], q8 = q[8], lam8 = 0.f;
  const f32x2 nav = {-alpha, -alpha};
  const f32x2 z2  = {0.f, 0.f};

  for (int it = 0; it < 300; ++it) {
    f32x2 pv0[4], pv1[4];
#pragma unroll
    for (int j = 0; j < 4; ++j) {
      pv0[j] = G0p[j] * lamp[j];
      pv1[j] = G1p[j] * lamp[j];
    }
    float pr08 = G08 * lam8, pr18 = G18 * lam8;
    // c.x = (p0+p1)+(p2+p3), c.y = (p4+p5)+(p6+p7): same tree as scalar ver.
    f32x2 c0 = (pv0[0] + pv0[1]) + (pv0[2] + pv0[3]);
    f32x2 c1 = (pv1[0] + pv1[1]) + (pv1[2] + pv1[3]);
    float t0 = (c0.x + c0.y) + pr08;
    float t1 = (c1.x + c1.y) + pr18;
    f32x2 t0v = {t0, t0}, t1v = {t1, t1};
#pragma unroll
    for (int j = 0; j < 4; ++j) {
      f32x2 g = __builtin_elementwise_fma(G0p[j], t0v,
                __builtin_elementwise_fma(G1p[j], t1v, qp2[j]));
      lamp[j] = __builtin_elementwise_max(
                __builtin_elementwise_fma(nav, g, lamp[j]), z2);
    }
    float g8 = fmaf(G08, t0, fmaf(G18, t1, q8));
    lam8 = fmaxf(fmaf(-alpha, g8, lam8), 0.f);
  }

  float u0 = -p0, u1 = -p1v;
#pragma unroll
  for (int j = 0; j < 4; ++j) {            // m = 0..3
    u0 = fmaf(-G0p[j].x, lamp[j].x, u0);
    u1 = fmaf(-G1p[j].x, lamp[j].x, u1);
  }
#pragma unroll
  for (int j = 0; j < 4; ++j) {            // m = 4..7
    u0 = fmaf(-G0p[j].y, lamp[j].y, u0);
    u1 = fmaf(-G1p[j].y, lamp[j].y, u1);
  }
  u0 = fmaf(-G08, lam8, u0);               // m = 8
  u1 = fmaf(-G18, lam8, u1);
  *(f32x2*)(out + 2 * (size_t)r) = f32x2{u0, u1};
}

// ---------------------------------------------------------------------------
extern "C" void kernel_launch(void* const* d_in, const int* in_sizes, int n_in,
                              void* d_out, int out_size, void* d_ws, size_t ws_size,
                              hipStream_t stream) {
  const float* x    = (const float*)d_in[0];
  const float* mean_= (const float*)d_in[1];
  const float* std_ = (const float*)d_in[2];
  const float* W1   = (const float*)d_in[3];
  const float* b1   = (const float*)d_in[4];
  const float* W21  = (const float*)d_in[5];
  const float* b21  = (const float*)d_in[6];
  const float* W22  = (const float*)d_in[7];
  const float* b22  = (const float*)d_in[8];
  // d_in[9],[10] = W23,b23 : dead code in reference (x33 unused)
  const float* W31  = (const float*)d_in[11];
  const float* b31  = (const float*)d_in[12];
  const float* W32  = (const float*)d_in[13];
  const float* b32  = (const float*)d_in[14];
  // d_in[15],[16] = W33,b33 : dead code
  const float* obst = (const float*)d_in[17];
  float* out = (float*)d_out;

  char* ws = (char*)d_ws;
  u16*   Wt   = (u16*)ws;                                   // 2 MB
  u16*   h1   = (u16*)(ws + (size_t)(1 << 21));             // 16 MB
  float* head = (float*)(ws + (size_t)(1 << 21) + (size_t)(1 << 24)); // 128 KB

  k_prep<<<256 + 512, 256, 0, stream>>>(W21, W22, Wt, x, W1, b1, h1, head);
  k_gemm<<<dim3(32, 8), 512, 0, stream>>>(h1, Wt, b21, b22, W31, W32, head);
  k_qp  <<<32, 256, 0, stream>>>(x, mean_, std_, head, b31, b32, obst, out);
}

// Round 4
// 171.488 us; speedup vs baseline: 1.0334x; 1.0334x over previous
//
#include <hip/hip_runtime.h>
#include <cstdint>
#include <cstddef>

typedef unsigned short u16;
typedef u16   u16x8  __attribute__((ext_vector_type(8)));
typedef u16   u16x4  __attribute__((ext_vector_type(4)));
typedef __bf16 bf16x8 __attribute__((ext_vector_type(8)));
typedef float f32x4  __attribute__((ext_vector_type(4)));
typedef float f32x2  __attribute__((ext_vector_type(2)));

__device__ __forceinline__ u16 f2bf(float f) {
  unsigned int x = __builtin_bit_cast(unsigned int, f);
  x += 0x7fffu + ((x >> 16) & 1u);   // RNE
  return (u16)(x >> 16);
}

// ---------------------------------------------------------------------------
// Fragment-subtile layout (both h1 and Wt): matrix [R rows][1024 k] bf16 is
// stored as 1KB subtiles (rt = r>>4, k32 = k>>5); inside a subtile, lane
// l = (kq = (k>>3)&3)*16 + (r&15) owns the 16B chunk k = k32*32+kq*8..+7.
// This is EXACTLY the mfma_16x16x32 A/B operand mapping, so k_gemm loads
// fragments as coalesced global_load_dwordx4 (lane offset = l*16B) straight
// from L2 -- no LDS, no barriers, no DMA in the GEMM at all.
// u16 offset of subtile (rt,k32) = (rt*32 + k32)*512; lane offset = l*8.
// ---------------------------------------------------------------------------

// ---------------------------------------------------------------------------
// Kernel 1: blocks 0..255   -> transpose W21/W22 -> Wt in frag layout
//           blocks 256..767 -> h1 = relu(x@W1+b1), one 16-row tile per block,
//                              computed with the verified FMA chains, staged
//                              through LDS (XOR-chunk swizzle, 2-way banks =
//                              free) and stored frag-coalesced (1KB/wave).
//                              Also zeroes head rows (ws poisoned).
// ---------------------------------------------------------------------------
__global__ __launch_bounds__(256) void k_prep(const float* __restrict__ W21,
                                              const float* __restrict__ W22,
                                              u16* __restrict__ Wtf,
                                              const float* __restrict__ x,
                                              const float* __restrict__ W1,
                                              const float* __restrict__ b1,
                                              u16* __restrict__ h1f,
                                              float* __restrict__ head) {
  __shared__ u16 smem[16 * 1024];          // 32 KB (transpose path aliases 64x65)
  const int b  = blockIdx.x;
  const int t  = threadIdx.x;
  const int l  = t & 63, wv = t >> 6;
  const int lrow = l & 15, kq = l >> 4;

  if (b < 256) {
    // ---- W21/W22 transpose -> Wt frag layout ----
    u16 (*s)[65] = (u16(*)[65])smem;       // s[k-local][n-local]
    const int mat = b >> 7;
    const int tt  = b & 127;
    const int k0  = (tt >> 3) * 64;        // 16 k-panels of 64
    const int n0  = (tt & 7) * 64;         // 8 n-panels of 64
    const float* W = mat ? W22 : W21;
    const int tx = t & 63;
    const int ty = t >> 6;
#pragma unroll
    for (int i = 0; i < 16; ++i) {
      int r = i * 4 + ty;
      s[r][tx] = f2bf(W[(size_t)(k0 + r) * 512 + n0 + tx]);
    }
    __syncthreads();
    // 8 subtiles in this 64n x 64k region: wave wv owns ntile wv, both k32l.
    const int ntg0  = (mat * 512 + n0) >> 4;   // + wv
    const int k32g0 = k0 >> 5;                 // + k32l
#pragma unroll
    for (int k32l = 0; k32l < 2; ++k32l) {
      u16x8 v;
#pragma unroll
      for (int e = 0; e < 8; ++e)
        v[e] = s[k32l * 32 + kq * 8 + e][wv * 16 + lrow];
      *(u16x8*)(Wtf + (size_t)((ntg0 + wv) * 32 + k32g0 + k32l) * 512 + l * 8) = v;
    }
  } else {
    // ---- h1 tile (16 rows) -> frag layout ----
    const int mt    = b - 256;               // 0..511
    const int row0t = mt * 16;
    if (t < 16)
      *(f32x4*)(head + 4 * (size_t)(row0t + t)) = f32x4{0.f, 0.f, 0.f, 0.f};
    const int c4 = t * 4;                    // thread owns cols 4t..4t+3
    f32x4 bv = *(const f32x4*)(b1 + c4);
    for (int g = 0; g < 2; ++g) {
      const int row0 = row0t + g * 8;
      f32x4 acc[8];
#pragma unroll
      for (int r = 0; r < 8; ++r) acc[r] = bv;
#pragma unroll
      for (int f = 0; f < 8; ++f) {
        f32x4 wvv = *(const f32x4*)(W1 + f * 1024 + c4);
#pragma unroll
        for (int r = 0; r < 8; ++r) {
          float xv = x[(size_t)(row0 + r) * 8 + f];   // block-uniform -> s_load
#pragma unroll
          for (int e = 0; e < 4; ++e) acc[r][e] = fmaf(xv, wvv[e], acc[r][e]);
        }
      }
      // store to LDS, chunk-swizzled: chunk c' = c ^ (row&7), 16B units intact
#pragma unroll
      for (int rr = 0; rr < 8; ++rr) {
        u16x4 o;
#pragma unroll
        for (int e = 0; e < 4; ++e) o[e] = f2bf(fmaxf(acc[rr][e], 0.f));
        const int r  = g * 8 + rr;
        const int cc = (t >> 1) ^ (r & 7);   // chunk = (4t)/8 = t>>1
        *(u16x4*)(smem + r * 1024 + cc * 8 + (t & 1) * 4) = o;
      }
    }
    __syncthreads();
    // frag-store: wave wv writes k32 = wv, wv+4, ..., wv+28 (1KB coalesced)
#pragma unroll
    for (int i = 0; i < 8; ++i) {
      const int k32 = wv + i * 4;
      const int cc  = (k32 * 4 + kq) ^ (lrow & 7);
      u16x8 v = *(const u16x8*)(smem + lrow * 1024 + cc * 8);
      *(u16x8*)(h1f + (size_t)(mt * 32 + k32) * 512 + l * 8) = v;
    }
  }
}

// ---------------------------------------------------------------------------
// Kernel 2: X2-GEMM direct-from-L2, ZERO LDS / ZERO barriers.
// Grid 32x8 = 256 blocks (1/CU), 4 waves/block; wave tile = 64 rows x 128
// cols; acc[4][8] f32x4. Per k32 step: 4 A-frag + 8 B-frag coalesced
// global_load_dwordx4 (L2/L1 hits: per-XCD working set A 2MB + B 2MB) + 32
// MFMA. No sync anywhere -> loads pipeline freely across iterations.
// k32 ascends 0..31 with identical per-step MFMA order as the verified
// kernel -> accumulators bit-exact. Fused head epilogue: two 64-col halves
// per wave, each reduced+atomicAdd'd exactly like the old wc=0/1 waves ->
// same addend multiset into head.
// ---------------------------------------------------------------------------
__global__ __launch_bounds__(256) void k_gemm(const u16* __restrict__ Af,
                                              const u16* __restrict__ Bf,
                                              const float* __restrict__ b21,
                                              const float* __restrict__ b22,
                                              const float* __restrict__ W31,
                                              const float* __restrict__ W32,
                                              float* __restrict__ head) {
  const int t = threadIdx.x, l = t & 63, wv = t >> 6;
  const int lrow = l & 15, kq = l >> 4;
  const int col0 = blockIdx.y * 128;
  // wave rows: blockIdx.x*256 + wv*64; mt base = bx*16 + wv*4
  const u16* Ab = Af + (size_t)((blockIdx.x * 16 + wv * 4) * 32) * 512 + l * 8;
  const u16* Bb = Bf + (size_t)((blockIdx.y * 8) * 32) * 512 + l * 8;

  f32x4 acc[4][8];
#pragma unroll
  for (int i = 0; i < 4; ++i)
#pragma unroll
    for (int j = 0; j < 8; ++j) acc[i][j] = f32x4{0.f, 0.f, 0.f, 0.f};

#pragma unroll 2
  for (int k32 = 0; k32 < 32; ++k32) {
    bf16x8 af[4], bfr[8];
#pragma unroll
    for (int i = 0; i < 4; ++i)
      af[i] = __builtin_bit_cast(bf16x8,
          *(const u16x8*)(Ab + (i * 32 + k32) * 512));
#pragma unroll
    for (int j = 0; j < 8; ++j)
      bfr[j] = __builtin_bit_cast(bf16x8,
          *(const u16x8*)(Bb + (j * 32 + k32) * 512));
#pragma unroll
    for (int i = 0; i < 4; ++i)
#pragma unroll
      for (int j = 0; j < 8; ++j)
        acc[i][j] = __builtin_amdgcn_mfma_f32_16x16x32_bf16(af[i], bfr[j], acc[i][j], 0, 0, 0);
  }

  // ---- fused head epilogue ----
  // acc[i][j][rr]: row = bx*256 + wv*64 + i*16 + kq*4 + rr,
  //                col = col0 + j*16 + lrow   (j = 0..7)
  const bool isX21 = (col0 < 512);
  const float* Wh  = isX21 ? W31 : W32;      // [512][2] row-major
  const int   hoff = isX21 ? 0 : 2;

#pragma unroll
  for (int half = 0; half < 2; ++half) {
    float hx[16], hy[16];
#pragma unroll
    for (int n = 0; n < 16; ++n) { hx[n] = 0.f; hy[n] = 0.f; }
#pragma unroll
    for (int jj = 0; jj < 4; ++jj) {
      const int j    = half * 4 + jj;
      const int col  = col0 + j * 16 + lrow;
      const int wcol = col & 511;
      f32x2 wvv = *(const f32x2*)(Wh + 2 * wcol);
      float bias = isX21 ? b21[col] : b22[wcol];
#pragma unroll
      for (int i = 0; i < 4; ++i)
#pragma unroll
        for (int rr = 0; rr < 4; ++rr) {
          float v = fmaxf(acc[i][j][rr] + bias, 0.f);
          hx[i * 4 + rr] = fmaf(v, wvv[0], hx[i * 4 + rr]);
          hy[i * 4 + rr] = fmaf(v, wvv[1], hy[i * 4 + rr]);
        }
    }
    // reduce across the 16 col-lanes (masks 1,2,4,8 stay inside the group)
#pragma unroll
    for (int m = 1; m <= 8; m <<= 1) {
#pragma unroll
      for (int n = 0; n < 16; ++n) {
        hx[n] += __shfl_xor(hx[n], m, 64);
        hy[n] += __shfl_xor(hy[n], m, 64);
      }
    }
    if (lrow == 0) {
#pragma unroll
      for (int i = 0; i < 4; ++i)
#pragma unroll
        for (int rr = 0; rr < 4; ++rr) {
          int row = blockIdx.x * 256 + wv * 64 + i * 16 + kq * 4 + rr;
          atomicAdd(head + 4 * (size_t)row + hoff,     hx[i * 4 + rr]);
          atomicAdd(head + 4 * (size_t)row + hoff + 1, hy[i * 4 + rr]);
        }
    }
  }
}

// ---------------------------------------------------------------------------
// Kernel 3: rank-2 dual PGD QP. One thread per row; heads precomputed.
// Inner loop packed as f32x2 pairs (m, m+4) -> v_pk_{mul,add,fma,max}_f32.
// Sum trees and op order bit-identical to the scalar version (verified R1/R2:
// absmax unchanged at 0.015625).
// ---------------------------------------------------------------------------
__global__ __launch_bounds__(256) void k_qp(const float* __restrict__ x,
                                            const float* __restrict__ mean_,
                                            const float* __restrict__ std_,
                                            const float* __restrict__ head,
                                            const float* __restrict__ b31,
                                            const float* __restrict__ b32,
                                            const float* __restrict__ obstacles,
                                            float* __restrict__ out) {
  const int r = blockIdx.x * 256 + threadIdx.x;
  f32x4 hd = *(const f32x4*)(head + 4 * (size_t)r);
  float p0  = hd[0] + b31[0];
  float p1v = hd[1] + b31[1];
  float pp1 = 4.f / (1.f + expf(-(hd[2] + b32[0])));
  float pp2 = 4.f / (1.f + expf(-(hd[3] + b32[1])));

  const f32x4* xp = (const f32x4*)(x + (size_t)r * 8);
  f32x4 xa = xp[0], xb = xp[1];
  float px = xa[0] * std_[0] + mean_[0];
  float py = xa[1] * std_[1] + mean_[1];
  float th = xa[2] * std_[2] + mean_[2];
  float v  = xa[3] * std_[3] + mean_[3];
  float ax = xb[0] * std_[4] + mean_[4];
  float ay = xb[1] * std_[5] + mean_[5];
  float st = sinf(th), ct = cosf(th);
  float Lf2b = 2.f * v * v;

  float G0[9], G1[9], q[9];
  float s00 = 0.f, s01 = 0.f, s11 = 0.f;
#pragma unroll
  for (int m = 0; m < 9; ++m) {
    float ox, oy, orad;
    if (m < 8) {
      ox = obstacles[m * 3]; oy = obstacles[m * 3 + 1]; orad = obstacles[m * 3 + 2];
    } else { ox = ax; oy = ay; orad = 0.5f; }
    float R  = 0.6f + orad;                  // AGENT_RADIUS + orad + SAFETY
    float dx = px - ox, dy = py - oy;
    float bar  = dx * dx + dy * dy - R * R;
    float dct  = dx * ct + dy * st;
    float bdot = 2.f * v * dct;
    float g0 = 2.f * v * (dx * st - dy * ct);   // -LgLfbu1
    float g1 = -2.f * dct;                      // -LgLfbu2
    float h  = Lf2b + (pp1 + pp2) * bdot + pp1 * pp2 * bar;
    G0[m] = g0; G1[m] = g1;
    q[m] = g0 * p0 + g1 * p1v + h;
    s00 += g0 * g0; s01 += g0 * g1; s11 += g1 * g1;
  }
  float L = sqrtf(s00 * s00 + 2.f * s01 * s01 + s11 * s11) + 1e-6f;
  float alpha = 1.f / L;

  // pack pairs (m, m+4); m=8 stays scalar
  f32x2 G0p[4], G1p[4], qp2[4], lamp[4];
#pragma unroll
  for (int j = 0; j < 4; ++j) {
    G0p[j] = f32x2{G0[j], G0[j + 4]};
    G1p[j] = f32x2{G1[j], G1[j + 4]};
    qp2[j] = f32x2{q[j],  q[j + 4]};
    lamp[j] = f32x2{0.f, 0.f};
  }
  float G08 = G0[8], G18 = G1[8], q8 = q[8], lam8 = 0.f;
  const f32x2 nav = {-alpha, -alpha};
  const f32x2 z2  = {0.f, 0.f};

  for (int it = 0; it < 300; ++it) {
    f32x2 pv0[4], pv1[4];
#pragma unroll
    for (int j = 0; j < 4; ++j) {
      pv0[j] = G0p[j] * lamp[j];
      pv1[j] = G1p[j] * lamp[j];
    }
    float pr08 = G08 * lam8, pr18 = G18 * lam8;
    // c.x = (p0+p1)+(p2+p3), c.y = (p4+p5)+(p6+p7): same tree as scalar ver.
    f32x2 c0 = (pv0[0] + pv0[1]) + (pv0[2] + pv0[3]);
    f32x2 c1 = (pv1[0] + pv1[1]) + (pv1[2] + pv1[3]);
    float t0 = (c0.x + c0.y) + pr08;
    float t1 = (c1.x + c1.y) + pr18;
    f32x2 t0v = {t0, t0}, t1v = {t1, t1};
#pragma unroll
    for (int j = 0; j < 4; ++j) {
      f32x2 g = __builtin_elementwise_fma(G0p[j], t0v,
                __builtin_elementwise_fma(G1p[j], t1v, qp2[j]));
      lamp[j] = __builtin_elementwise_max(
                __builtin_elementwise_fma(nav, g, lamp[j]), z2);
    }
    float g8 = fmaf(G08, t0, fmaf(G18, t1, q8));
    lam8 = fmaxf(fmaf(-alpha, g8, lam8), 0.f);
  }

  float u0 = -p0, u1 = -p1v;
#pragma unroll
  for (int j = 0; j < 4; ++j) {            // m = 0..3
    u0 = fmaf(-G0p[j].x, lamp[j].x, u0);
    u1 = fmaf(-G1p[j].x, lamp[j].x, u1);
  }
#pragma unroll
  for (int j = 0; j < 4; ++j) {            // m = 4..7
    u0 = fmaf(-G0p[j].y, lamp[j].y, u0);
    u1 = fmaf(-G1p[j].y, lamp[j].y, u1);
  }
  u0 = fmaf(-G08, lam8, u0);               // m = 8
  u1 = fmaf(-G18, lam8, u1);
  *(f32x2*)(out + 2 * (size_t)r) = f32x2{u0, u1};
}

// ---------------------------------------------------------------------------
extern "C" void kernel_launch(void* const* d_in, const int* in_sizes, int n_in,
                              void* d_out, int out_size, void* d_ws, size_t ws_size,
                              hipStream_t stream) {
  const float* x    = (const float*)d_in[0];
  const float* mean_= (const float*)d_in[1];
  const float* std_ = (const float*)d_in[2];
  const float* W1   = (const float*)d_in[3];
  const float* b1   = (const float*)d_in[4];
  const float* W21  = (const float*)d_in[5];
  const float* b21  = (const float*)d_in[6];
  const float* W22  = (const float*)d_in[7];
  const float* b22  = (const float*)d_in[8];
  // d_in[9],[10] = W23,b23 : dead code in reference (x33 unused)
  const float* W31  = (const float*)d_in[11];
  const float* b31  = (const float*)d_in[12];
  const float* W32  = (const float*)d_in[13];
  const float* b32  = (const float*)d_in[14];
  // d_in[15],[16] = W33,b33 : dead code
  const float* obst = (const float*)d_in[17];
  float* out = (float*)d_out;

  char* ws = (char*)d_ws;
  u16*   Wtf  = (u16*)ws;                                   // 2 MB frag layout
  u16*   h1f  = (u16*)(ws + (size_t)(1 << 21));             // 16 MB frag layout
  float* head = (float*)(ws + (size_t)(1 << 21) + (size_t)(1 << 24)); // 128 KB

  k_prep<<<256 + 512, 256, 0, stream>>>(W21, W22, Wtf, x, W1, b1, h1f, head);
  k_gemm<<<dim3(32, 8), 256, 0, stream>>>(h1f, Wtf, b21, b22, W31, W32, head);
  k_qp  <<<32, 256, 0, stream>>>(x, mean_, std_, head, b31, b32, obst, out);
}

// Round 5
// 166.426 us; speedup vs baseline: 1.0648x; 1.0304x over previous
//
#include <hip/hip_runtime.h>
#include <cstdint>
#include <cstddef>

typedef unsigned short u16;
typedef u16   u16x8  __attribute__((ext_vector_type(8)));
typedef u16   u16x4  __attribute__((ext_vector_type(4)));
typedef __bf16 bf16x8 __attribute__((ext_vector_type(8)));
typedef float f32x4  __attribute__((ext_vector_type(4)));
typedef float f32x2  __attribute__((ext_vector_type(2)));

__device__ __forceinline__ u16 f2bf(float f) {
  unsigned int x = __builtin_bit_cast(unsigned int, f);
  x += 0x7fffu + ((x >> 16) & 1u);   // RNE
  return (u16)(x >> 16);
}

// ---------------------------------------------------------------------------
// Fragment-subtile layout (both h1 and Wt): matrix [R rows][1024 k] bf16 is
// stored as 1KB subtiles (rt = r>>4, k32 = k>>5); inside a subtile, lane
// l = (kq = (k>>3)&3)*16 + (r&15) owns the 16B chunk k = k32*32+kq*8..+7.
// This is EXACTLY the mfma_16x16x32 A/B operand mapping, so k_gemm loads
// fragments as coalesced global_load_dwordx4 (lane offset = l*16B) straight
// from L2 -- no LDS, no barriers, no DMA in the GEMM at all.
// u16 offset of subtile (rt,k32) = (rt*32 + k32)*512; lane offset = l*8.
// ---------------------------------------------------------------------------

// ---------------------------------------------------------------------------
// Kernel 1: blocks 0..255   -> transpose W21/W22 -> Wt in frag layout
//           blocks 256..767 -> h1 = relu(x@W1+b1), one 16-row tile per block,
//                              verified FMA chains, staged through LDS
//                              (XOR-chunk swizzle) and stored frag-coalesced.
//                              Also zeroes head rows (ws poisoned).
// (unchanged from R4 -- verified pass, absmax 0.015625)
// ---------------------------------------------------------------------------
__global__ __launch_bounds__(256) void k_prep(const float* __restrict__ W21,
                                              const float* __restrict__ W22,
                                              u16* __restrict__ Wtf,
                                              const float* __restrict__ x,
                                              const float* __restrict__ W1,
                                              const float* __restrict__ b1,
                                              u16* __restrict__ h1f,
                                              float* __restrict__ head) {
  __shared__ u16 smem[16 * 1024];          // 32 KB (transpose path aliases 64x65)
  const int b  = blockIdx.x;
  const int t  = threadIdx.x;
  const int l  = t & 63, wv = t >> 6;
  const int lrow = l & 15, kq = l >> 4;

  if (b < 256) {
    // ---- W21/W22 transpose -> Wt frag layout ----
    u16 (*s)[65] = (u16(*)[65])smem;       // s[k-local][n-local]
    const int mat = b >> 7;
    const int tt  = b & 127;
    const int k0  = (tt >> 3) * 64;        // 16 k-panels of 64
    const int n0  = (tt & 7) * 64;         // 8 n-panels of 64
    const float* W = mat ? W22 : W21;
    const int tx = t & 63;
    const int ty = t >> 6;
#pragma unroll
    for (int i = 0; i < 16; ++i) {
      int r = i * 4 + ty;
      s[r][tx] = f2bf(W[(size_t)(k0 + r) * 512 + n0 + tx]);
    }
    __syncthreads();
    // 8 subtiles in this 64n x 64k region: wave wv owns ntile wv, both k32l.
    const int ntg0  = (mat * 512 + n0) >> 4;   // + wv
    const int k32g0 = k0 >> 5;                 // + k32l
#pragma unroll
    for (int k32l = 0; k32l < 2; ++k32l) {
      u16x8 v;
#pragma unroll
      for (int e = 0; e < 8; ++e)
        v[e] = s[k32l * 32 + kq * 8 + e][wv * 16 + lrow];
      *(u16x8*)(Wtf + (size_t)((ntg0 + wv) * 32 + k32g0 + k32l) * 512 + l * 8) = v;
    }
  } else {
    // ---- h1 tile (16 rows) -> frag layout ----
    const int mt    = b - 256;               // 0..511
    const int row0t = mt * 16;
    if (t < 16)
      *(f32x4*)(head + 4 * (size_t)(row0t + t)) = f32x4{0.f, 0.f, 0.f, 0.f};
    const int c4 = t * 4;                    // thread owns cols 4t..4t+3
    f32x4 bv = *(const f32x4*)(b1 + c4);
    for (int g = 0; g < 2; ++g) {
      const int row0 = row0t + g * 8;
      f32x4 acc[8];
#pragma unroll
      for (int r = 0; r < 8; ++r) acc[r] = bv;
#pragma unroll
      for (int f = 0; f < 8; ++f) {
        f32x4 wvv = *(const f32x4*)(W1 + f * 1024 + c4);
#pragma unroll
        for (int r = 0; r < 8; ++r) {
          float xv = x[(size_t)(row0 + r) * 8 + f];   // block-uniform -> s_load
#pragma unroll
          for (int e = 0; e < 4; ++e) acc[r][e] = fmaf(xv, wvv[e], acc[r][e]);
        }
      }
      // store to LDS, chunk-swizzled: chunk c' = c ^ (row&7), 16B units intact
#pragma unroll
      for (int rr = 0; rr < 8; ++rr) {
        u16x4 o;
#pragma unroll
        for (int e = 0; e < 4; ++e) o[e] = f2bf(fmaxf(acc[rr][e], 0.f));
        const int r  = g * 8 + rr;
        const int cc = (t >> 1) ^ (r & 7);   // chunk = (4t)/8 = t>>1
        *(u16x4*)(smem + r * 1024 + cc * 8 + (t & 1) * 4) = o;
      }
    }
    __syncthreads();
    // frag-store: wave wv writes k32 = wv, wv+4, ..., wv+28 (1KB coalesced)
#pragma unroll
    for (int i = 0; i < 8; ++i) {
      const int k32 = wv + i * 4;
      const int cc  = (k32 * 4 + kq) ^ (lrow & 7);
      u16x8 v = *(const u16x8*)(smem + lrow * 1024 + cc * 8);
      *(u16x8*)(h1f + (size_t)(mt * 32 + k32) * 512 + l * 8) = v;
    }
  }
}

// ---------------------------------------------------------------------------
// Kernel 2: X2-GEMM direct-from-L2, ZERO LDS / ZERO barriers.
// R4 post-mortem: 64x128 wave tile capped the machine at 4 waves/CU
// (1/SIMD) -> 76 cyc/load-instr latency exposure, MfmaUtil 12%. Fix:
// wave tile 64x64 (acc[4][4] = 64 VGPR), 4-wave blocks of 128x128,
// grid 64x8 = 512 blocks -> 2 blocks/CU, 8 waves/CU, 2/SIMD. Per k32:
// 4 A-frag + 4 B-frag coalesced dwordx4 + 16 MFMA; A/B frags each shared
// by 2 waves of the block via L1. Per-output k32 chain still ascending
// 0..31 on identical bf16 fragments -> accumulators bit-exact vs R2/R4;
// epilogue is R2's verbatim (same addend multiset into head).
// ---------------------------------------------------------------------------
__global__ __launch_bounds__(256) void k_gemm(const u16* __restrict__ Af,
                                              const u16* __restrict__ Bf,
                                              const float* __restrict__ b21,
                                              const float* __restrict__ b22,
                                              const float* __restrict__ W31,
                                              const float* __restrict__ W32,
                                              float* __restrict__ head) {
  const int t = threadIdx.x, l = t & 63, wv = t >> 6;
  const int lrow = l & 15, kq = l >> 4;
  const int wr = wv >> 1, wc = wv & 1;     // 2x2 wave grid, 64x64 per wave
  const int col0 = blockIdx.y * 128;
  // wave rows: blockIdx.x*128 + wr*64 -> rt base = bx*8 + wr*4
  const u16* Ab = Af + (size_t)((blockIdx.x * 8 + wr * 4) * 32) * 512 + l * 8;
  // wave cols: col0 + wc*64 -> nt base = by*8 + wc*4
  const u16* Bb = Bf + (size_t)((blockIdx.y * 8 + wc * 4) * 32) * 512 + l * 8;

  f32x4 acc[4][4];
#pragma unroll
  for (int i = 0; i < 4; ++i)
#pragma unroll
    for (int j = 0; j < 4; ++j) acc[i][j] = f32x4{0.f, 0.f, 0.f, 0.f};

#pragma unroll 2
  for (int k32 = 0; k32 < 32; ++k32) {
    bf16x8 af[4], bfr[4];
#pragma unroll
    for (int i = 0; i < 4; ++i)
      af[i] = __builtin_bit_cast(bf16x8,
          *(const u16x8*)(Ab + (i * 32 + k32) * 512));
#pragma unroll
    for (int j = 0; j < 4; ++j)
      bfr[j] = __builtin_bit_cast(bf16x8,
          *(const u16x8*)(Bb + (j * 32 + k32) * 512));
#pragma unroll
    for (int i = 0; i < 4; ++i)
#pragma unroll
      for (int j = 0; j < 4; ++j)
        acc[i][j] = __builtin_amdgcn_mfma_f32_16x16x32_bf16(af[i], bfr[j], acc[i][j], 0, 0, 0);
  }

  // ---- fused head epilogue (R2 verbatim) ----
  // acc[i][j][rr]: row = bx*128 + wr*64 + i*16 + kq*4 + rr,
  //                col = col0 + wc*64 + j*16 + lrow
  const bool isX21 = (col0 < 512);
  const float* Wh  = isX21 ? W31 : W32;      // [512][2] row-major
  const int   hoff = isX21 ? 0 : 2;

  float hx[16], hy[16];
#pragma unroll
  for (int n = 0; n < 16; ++n) { hx[n] = 0.f; hy[n] = 0.f; }
#pragma unroll
  for (int j = 0; j < 4; ++j) {
    int col  = col0 + wc * 64 + j * 16 + lrow;
    int wcol = col & 511;
    f32x2 wvv = *(const f32x2*)(Wh + 2 * wcol);
    float bias = isX21 ? b21[col] : b22[wcol];
#pragma unroll
    for (int i = 0; i < 4; ++i)
#pragma unroll
      for (int rr = 0; rr < 4; ++rr) {
        float v = fmaxf(acc[i][j][rr] + bias, 0.f);
        hx[i * 4 + rr] = fmaf(v, wvv[0], hx[i * 4 + rr]);
        hy[i * 4 + rr] = fmaf(v, wvv[1], hy[i * 4 + rr]);
      }
  }
  // reduce across the 16 col-lanes (masks 1,2,4,8 stay inside the group)
#pragma unroll
  for (int m = 1; m <= 8; m <<= 1) {
#pragma unroll
    for (int n = 0; n < 16; ++n) {
      hx[n] += __shfl_xor(hx[n], m, 64);
      hy[n] += __shfl_xor(hy[n], m, 64);
    }
  }
  if (lrow == 0) {
#pragma unroll
    for (int i = 0; i < 4; ++i)
#pragma unroll
      for (int rr = 0; rr < 4; ++rr) {
        int row = blockIdx.x * 128 + wr * 64 + i * 16 + kq * 4 + rr;
        atomicAdd(head + 4 * (size_t)row + hoff,     hx[i * 4 + rr]);
        atomicAdd(head + 4 * (size_t)row + hoff + 1, hy[i * 4 + rr]);
      }
  }
}

// ---------------------------------------------------------------------------
// Kernel 3: rank-2 dual PGD QP. One thread per row; heads precomputed.
// Inner loop packed as f32x2 pairs (m, m+4) -> v_pk_{mul,add,fma,max}_f32.
// Sum trees and op order bit-identical to the scalar version (verified
// R1/R2/R3/R4: absmax unchanged at 0.015625).
// ---------------------------------------------------------------------------
__global__ __launch_bounds__(256) void k_qp(const float* __restrict__ x,
                                            const float* __restrict__ mean_,
                                            const float* __restrict__ std_,
                                            const float* __restrict__ head,
                                            const float* __restrict__ b31,
                                            const float* __restrict__ b32,
                                            const float* __restrict__ obstacles,
                                            float* __restrict__ out) {
  const int r = blockIdx.x * 256 + threadIdx.x;
  f32x4 hd = *(const f32x4*)(head + 4 * (size_t)r);
  float p0  = hd[0] + b31[0];
  float p1v = hd[1] + b31[1];
  float pp1 = 4.f / (1.f + expf(-(hd[2] + b32[0])));
  float pp2 = 4.f / (1.f + expf(-(hd[3] + b32[1])));

  const f32x4* xp = (const f32x4*)(x + (size_t)r * 8);
  f32x4 xa = xp[0], xb = xp[1];
  float px = xa[0] * std_[0] + mean_[0];
  float py = xa[1] * std_[1] + mean_[1];
  float th = xa[2] * std_[2] + mean_[2];
  float v  = xa[3] * std_[3] + mean_[3];
  float ax = xb[0] * std_[4] + mean_[4];
  float ay = xb[1] * std_[5] + mean_[5];
  float st = sinf(th), ct = cosf(th);
  float Lf2b = 2.f * v * v;

  float G0[9], G1[9], q[9];
  float s00 = 0.f, s01 = 0.f, s11 = 0.f;
#pragma unroll
  for (int m = 0; m < 9; ++m) {
    float ox, oy, orad;
    if (m < 8) {
      ox = obstacles[m * 3]; oy = obstacles[m * 3 + 1]; orad = obstacles[m * 3 + 2];
    } else { ox = ax; oy = ay; orad = 0.5f; }
    float R  = 0.6f + orad;                  // AGENT_RADIUS + orad + SAFETY
    float dx = px - ox, dy = py - oy;
    float bar  = dx * dx + dy * dy - R * R;
    float dct  = dx * ct + dy * st;
    float bdot = 2.f * v * dct;
    float g0 = 2.f * v * (dx * st - dy * ct);   // -LgLfbu1
    float g1 = -2.f * dct;                      // -LgLfbu2
    float h  = Lf2b + (pp1 + pp2) * bdot + pp1 * pp2 * bar;
    G0[m] = g0; G1[m] = g1;
    q[m] = g0 * p0 + g1 * p1v + h;
    s00 += g0 * g0; s01 += g0 * g1; s11 += g1 * g1;
  }
  float L = sqrtf(s00 * s00 + 2.f * s01 * s01 + s11 * s11) + 1e-6f;
  float alpha = 1.f / L;

  // pack pairs (m, m+4); m=8 stays scalar
  f32x2 G0p[4], G1p[4], qp2[4], lamp[4];
#pragma unroll
  for (int j = 0; j < 4; ++j) {
    G0p[j] = f32x2{G0[j], G0[j + 4]};
    G1p[j] = f32x2{G1[j], G1[j + 4]};
    qp2[j] = f32x2{q[j],  q[j + 4]};
    lamp[j] = f32x2{0.f, 0.f};
  }
  float G08 = G0[8], G18 = G1[8], q8 = q[8], lam8 = 0.f;
  const f32x2 nav = {-alpha, -alpha};
  const f32x2 z2  = {0.f, 0.f};

  for (int it = 0; it < 300; ++it) {
    f32x2 pv0[4], pv1[4];
#pragma unroll
    for (int j = 0; j < 4; ++j) {
      pv0[j] = G0p[j] * lamp[j];
      pv1[j] = G1p[j] * lamp[j];
    }
    float pr08 = G08 * lam8, pr18 = G18 * lam8;
    // c.x = (p0+p1)+(p2+p3), c.y = (p4+p5)+(p6+p7): same tree as scalar ver.
    f32x2 c0 = (pv0[0] + pv0[1]) + (pv0[2] + pv0[3]);
    f32x2 c1 = (pv1[0] + pv1[1]) + (pv1[2] + pv1[3]);
    float t0 = (c0.x + c0.y) + pr08;
    float t1 = (c1.x + c1.y) + pr18;
    f32x2 t0v = {t0, t0}, t1v = {t1, t1};
#pragma unroll
    for (int j = 0; j < 4; ++j) {
      f32x2 g = __builtin_elementwise_fma(G0p[j], t0v,
                __builtin_elementwise_fma(G1p[j], t1v, qp2[j]));
      lamp[j] = __builtin_elementwise_max(
                __builtin_elementwise_fma(nav, g, lamp[j]), z2);
    }
    float g8 = fmaf(G08, t0, fmaf(G18, t1, q8));
    lam8 = fmaxf(fmaf(-alpha, g8, lam8), 0.f);
  }

  float u0 = -p0, u1 = -p1v;
#pragma unroll
  for (int j = 0; j < 4; ++j) {            // m = 0..3
    u0 = fmaf(-G0p[j].x, lamp[j].x, u0);
    u1 = fmaf(-G1p[j].x, lamp[j].x, u1);
  }
#pragma unroll
  for (int j = 0; j < 4; ++j) {            // m = 4..7
    u0 = fmaf(-G0p[j].y, lamp[j].y, u0);
    u1 = fmaf(-G1p[j].y, lamp[j].y, u1);
  }
  u0 = fmaf(-G08, lam8, u0);               // m = 8
  u1 = fmaf(-G18, lam8, u1);
  *(f32x2*)(out + 2 * (size_t)r) = f32x2{u0, u1};
}

// ---------------------------------------------------------------------------
extern "C" void kernel_launch(void* const* d_in, const int* in_sizes, int n_in,
                              void* d_out, int out_size, void* d_ws, size_t ws_size,
                              hipStream_t stream) {
  const float* x    = (const float*)d_in[0];
  const float* mean_= (const float*)d_in[1];
  const float* std_ = (const float*)d_in[2];
  const float* W1   = (const float*)d_in[3];
  const float* b1   = (const float*)d_in[4];
  const float* W21  = (const float*)d_in[5];
  const float* b21  = (const float*)d_in[6];
  const float* W22  = (const float*)d_in[7];
  const float* b22  = (const float*)d_in[8];
  // d_in[9],[10] = W23,b23 : dead code in reference (x33 unused)
  const float* W31  = (const float*)d_in[11];
  const float* b31  = (const float*)d_in[12];
  const float* W32  = (const float*)d_in[13];
  const float* b32  = (const float*)d_in[14];
  // d_in[15],[16] = W33,b33 : dead code
  const float* obst = (const float*)d_in[17];
  float* out = (float*)d_out;

  char* ws = (char*)d_ws;
  u16*   Wtf  = (u16*)ws;                                   // 2 MB frag layout
  u16*   h1f  = (u16*)(ws + (size_t)(1 << 21));             // 16 MB frag layout
  float* head = (float*)(ws + (size_t)(1 << 21) + (size_t)(1 << 24)); // 128 KB

  k_prep<<<256 + 512, 256, 0, stream>>>(W21, W22, Wtf, x, W1, b1, h1f, head);
  k_gemm<<<dim3(64, 8), 256, 0, stream>>>(h1f, Wtf, b21, b22, W31, W32, head);
  k_qp  <<<32, 256, 0, stream>>>(x, mean_, std_, head, b31, b32, obst, out);
}